// Round 14
// baseline (276.750 us; speedup 1.0000x reference)
//
#include <hip/hip_runtime.h>
#include <math.h>

#define B_ 2
#define C_ 128
#define NPIX_ 16384
#define HTH_ 184
#define HTW_ 180
#define NBINS_ 33120
#define PH_ 186
#define PW_ 184
#define NPB_ 1984
#define TOTN_ 3968
#define EPS_ 1e-5f

// stats region layout (floats)
#define ST_HC_SUM 0
#define ST_HC_SQ  128
#define ST_SC_SUM 256
#define ST_SC_SQ  448
#define ST_LOSS   640
#define ST_TICKET 652
#define ST_IMG_P1 704      // 8 chunks x 128 c
#define ST_IMG_P2 1728     // 8 chunks x 128 c

typedef __attribute__((ext_vector_type(8))) short v8s;
typedef __attribute__((ext_vector_type(4))) float v4f;

__device__ inline unsigned short f2b(float f) {
  unsigned u = __builtin_bit_cast(unsigned, f);
  unsigned r = u + 0x7fffu + ((u >> 16) & 1u);
  return (unsigned short)(r >> 16);
}
__device__ inline float b2f(unsigned short u) {
  unsigned v = ((unsigned)u) << 16;
  return __builtin_bit_cast(float, v);
}

// ---- KPREP0: weight permutes + htb border zero + img BN partials + st zero ----
__global__ void kprep0(const float* __restrict__ w, const float* __restrict__ dw,
                       const float* __restrict__ wsc,
                       unsigned short* __restrict__ wtb, unsigned short* __restrict__ dwb,
                       unsigned short* __restrict__ swb,
                       unsigned* __restrict__ htb2, const float* __restrict__ img,
                       float* __restrict__ st) {
  int bid = blockIdx.x;
  int tid = threadIdx.x;
  if (bid < 1612) {
    int idx = bid*256 + tid;
    if (idx < 147456) {
      int tap = idx >> 14, z = idx & 16383;
      int j = z & 7, lane = (z >> 3) & 63, nt = (z >> 9) & 7, kt = (z >> 12) & 3;
      int l = lane & 15, q = lane >> 4;
      int co = nt*16 + l, ci = kt*32 + q*8 + j;
      wtb[idx] = f2b(w[(tap*C_ + ci)*C_ + co]);
    } else if (idx < 245760) {
      int i2 = idx - 147456;                  // 98304
      int sl = i2 >> 13, z = i2 & 8191;
      int j = z & 7, lane = (z >> 3) & 63, nt = (z >> 9) & 3, kt = (z >> 11) & 3;
      int l = lane & 15, q = lane >> 4;
      int co = nt*16 + l, cc = kt*32 + q*8 + j;
      dwb[i2] = f2b(dw[(sl*128 + cc)*64 + co]);
    } else if (idx < 270336) {
      int i3 = idx - 245760;                  // 24576
      int s = i3 >> 13, z = i3 & 8191;
      int j = z & 7, lane = (z >> 3) & 63, nt = (z >> 9) & 3, kt = (z >> 11) & 3;
      int l = lane & 15, q = lane >> 4;
      int co = nt*16 + l, cc = kt*32 + q*8 + j;
      swb[i3] = f2b(wsc[(s*64 + co)*128 + cc]);
    } else if (idx < 412672) {
      int i = idx - 270336;                   // 142336
      int d = i & 63;
      int cell = i >> 6;                      // 2224
      int b = cell / 1112, j = cell % 1112;
      int y, x;
      if (j < 184) { y = 0; x = j; }
      else if (j < 368) { y = 185; x = j - 184; }
      else { int c = j - 368; int xi = c / 186; y = c % 186; x = xi == 0 ? 0 : 180 + xi; }
      htb2[((size_t)(b*PH_ + y)*PW_ + x)*64 + d] = 0u;
    }
  } else if (bid < 2636) {
    int kb = bid - 1612;                       // 1024 blocks: c = kb>>3, chunk = kb&7
    int c = kb >> 3, chunk = kb & 7;
    float s1 = 0.f, s2 = 0.f;
    for (int i = chunk*4096 + tid; i < (chunk+1)*4096; i += 256) {
      int b = i >> 14, p = i & (NPIX_-1);
      float v = img[((size_t)(b*C_ + c))*NPIX_ + p];
      s1 += v; s2 += v*v;
    }
    __shared__ float r1[256], r2[256];
    r1[tid] = s1; r2[tid] = s2; __syncthreads();
    for (int off = 128; off; off >>= 1) {
      if (tid < off) { r1[tid] += r1[tid+off]; r2[tid] += r2[tid+off]; }
      __syncthreads();
    }
    if (tid == 0) {
      st[ST_IMG_P1 + chunk*128 + c] = r1[0];
      st[ST_IMG_P2 + chunk*128 + c] = r2[0];
    }
  } else {
    // zero block: st[0..672) = HC/SC stats, LOSS, TICKET
    for (int i = tid; i < 672; i += 256) st[i] = 0.f;
  }
}

// ---- K2: img BN finalize + BN+ReLU + transpose NCHW -> bf16 [b][pix][c] ----
__global__ void k2_bnrelu_t(const float* __restrict__ img, const float* __restrict__ st,
                            const float* __restrict__ g, const float* __restrict__ be,
                            unsigned short* __restrict__ xt) {
  __shared__ float tile[32*65];
  __shared__ float ash[32], dsh[32];
  int p0 = blockIdx.x*64, c0 = blockIdx.y*32, b = blockIdx.z;
  int tid = threadIdx.x;
  if (tid < 32) {
    int c = c0 + tid;
    float s1 = 0.f, s2 = 0.f;
    #pragma unroll
    for (int ch = 0; ch < 8; ch++) {
      s1 += st[ST_IMG_P1 + ch*128 + c];
      s2 += st[ST_IMG_P2 + ch*128 + c];
    }
    float n = (float)(B_*NPIX_);
    float m = s1/n;
    float var = s2/n - m*m;
    float a = g[c]*rsqrtf(var + EPS_);
    ash[tid] = a; dsh[tid] = be[c] - a*m;
  }
  __syncthreads();
  for (int r = 0; r < 8; r++) {
    int flat = tid + r*256;
    int row = flat >> 6, col = flat & 63;
    float v = img[((size_t)(b*C_ + c0 + row))*NPIX_ + p0 + col];
    tile[row*65 + col] = fmaxf(ash[row]*v + dsh[row], 0.f);
  }
  __syncthreads();
  for (int r = 0; r < 4; r++) {
    int flat = (tid + r*256)*2;
    int pl = flat >> 5, cl = flat & 31;
    unsigned lo = f2b(tile[cl*65 + pl]);
    unsigned hi = f2b(tile[(cl+1)*65 + pl]);
    *(unsigned*)&xt[((size_t)b*NPIX_ + p0 + pl)*C_ + c0 + cl] = lo | (hi << 16);
  }
}

// ---- K3 v2: Hough gather, 4 bins/wave, 32 loads in flight ----
__global__ void k3_hough(const unsigned* __restrict__ xt2, const int* __restrict__ hidx,
                         const float* __restrict__ hwt, unsigned* __restrict__ htb2) {
  int tid = threadIdx.x;
  int wv = __builtin_amdgcn_readfirstlane(tid >> 6);
  int lane = tid & 63;
  int b = blockIdx.y;
  int bin0 = blockIdx.x*16 + wv*4;
  const unsigned* base = xt2 + (size_t)b*NPIX_*64 + lane;
  unsigned dv[4][8];
  #pragma unroll
  for (int i = 0; i < 4; i++) {
    #pragma unroll
    for (int k = 0; k < 8; k++) {
      int p = hidx[(bin0+i)*8 + k];
      dv[i][k] = base[(size_t)p*64];
    }
  }
  #pragma unroll
  for (int i = 0; i < 4; i++) {
    int bin = bin0 + i;
    float acc0 = 0.f, acc1 = 0.f;
    #pragma unroll
    for (int k = 0; k < 8; k++) {
      float w = hwt[bin*8 + k];
      acc0 += w * b2f((unsigned short)(dv[i][k] & 0xffff));
      acc1 += w * b2f((unsigned short)(dv[i][k] >> 16));
    }
    int y = bin / HTW_, x = bin - y*HTW_;
    htb2[((size_t)(b*PH_ + y + 1)*PW_ + (x+1))*64 + lane] =
        (unsigned)f2b(acc0) | (((unsigned)f2b(acc1)) << 16);
  }
}

// ---- K4 v10: R11 shape (wave = 32px x 128co, grid 518) + one-tap-ahead SW pipeline ----
__global__ __launch_bounds__(256, 2) void k4_mfma(
    const unsigned short* __restrict__ htb, const unsigned short* __restrict__ wtb,
    unsigned short* __restrict__ hcb, float* __restrict__ st) {
  __shared__ char smem[32768];             // 32 KB tap weights; reused as red[] in epilogue
  int tid = threadIdx.x;
  int wav = tid >> 6, lane = tid & 63;
  int quad = lane >> 4, l16 = lane & 15;
  int b = blockIdx.y;
  int p0 = blockIdx.x*128 + wav*32;
  size_t ab[2];
  #pragma unroll
  for (int t = 0; t < 2; t++) {
    int px = p0 + t*16 + l16; if (px > NBINS_-1) px = NBINS_-1;
    int y = px / HTW_, x = px % HTW_;
    ab[t] = (((size_t)(b*PH_ + y))*PW_ + x)*C_ + quad*8;
  }
  v4f acc[2][8];
  #pragma unroll
  for (int t = 0; t < 2; t++)
    #pragma unroll
    for (int nt = 0; nt < 8; nt++) acc[t][nt] = (v4f){0,0,0,0};

  // prologue: stage tap 0 weights + load tap 0 A-frags
  {
    const uint4* src = (const uint4*)wtb;
    uint4* dst = (uint4*)smem;
    #pragma unroll
    for (int s = 0; s < 8; s++) dst[tid + s*256] = src[tid + s*256];
  }
  v8s aCur[2][4];
  #pragma unroll
  for (int t = 0; t < 2; t++)
    #pragma unroll
    for (int kt = 0; kt < 4; kt++)
      aCur[t][kt] = *(const v8s*)&htb[ab[t] + kt*32];     // tap 0: toff = 0? no: dy=0,dx=0 -> toff=0
  __syncthreads();

  for (int tap = 0; tap < 9; tap++) {
    uint4 wreg[8];
    v8s aNext[2][4];
    if (tap < 8) {
      const uint4* src = (const uint4*)(wtb + (tap+1)*16384);
      #pragma unroll
      for (int s = 0; s < 8; s++) wreg[s] = src[tid + s*256];
      int dy = (tap+1)/3, dx = (tap+1) - dy*3;
      int toff = (dy*PW_ + dx)*C_;
      #pragma unroll
      for (int t = 0; t < 2; t++)
        #pragma unroll
        for (int kt = 0; kt < 4; kt++)
          aNext[t][kt] = *(const v8s*)&htb[ab[t] + toff + kt*32];
    }
    // MFMA phase: regs + LDS only (global latency of prefetches overlaps this)
    #pragma unroll
    for (int kt = 0; kt < 4; kt++) {
      #pragma unroll
      for (int nt = 0; nt < 8; nt++) {
        v8s bf = *(const v8s*)(smem + ((((kt*8 + nt)*64) + lane) << 4));
        acc[0][nt] = __builtin_amdgcn_mfma_f32_16x16x32_bf16(aCur[0][kt], bf, acc[0][nt], 0, 0, 0);
        acc[1][nt] = __builtin_amdgcn_mfma_f32_16x16x32_bf16(aCur[1][kt], bf, acc[1][nt], 0, 0, 0);
      }
    }
    __syncthreads();            // all waves done reading this tap's LDS
    if (tap < 8) {
      uint4* dst = (uint4*)smem;
      #pragma unroll
      for (int s = 0; s < 8; s++) dst[tid + s*256] = wreg[s];
      #pragma unroll
      for (int t = 0; t < 2; t++)
        #pragma unroll
        for (int kt = 0; kt < 4; kt++)
          aCur[t][kt] = aNext[t][kt];
    }
    __syncthreads();            // LDS writes visible before next MFMA phase
  }
  // epilogue: bf16 store + fused channel stats. D: row=quad*4+reg, col=l16
  float* red = (float*)smem;               // 128*17 floats = 8.7 KB
  float s1[8], s2[8];
  #pragma unroll
  for (int nt = 0; nt < 8; nt++) { s1[nt] = 0.f; s2[nt] = 0.f; }
  #pragma unroll
  for (int t = 0; t < 2; t++) {
    int pbase = p0 + t*16 + quad*4;
    #pragma unroll
    for (int nt = 0; nt < 8; nt++) {
      int co = nt*16 + l16;
      #pragma unroll
      for (int reg = 0; reg < 4; reg++) {
        int po = pbase + reg;
        if (po < NBINS_) {
          float v = acc[t][nt][reg];
          hcb[((size_t)b*NBINS_ + po)*C_ + co] = f2b(v);
          s1[nt] += v; s2[nt] += v*v;
        }
      }
    }
  }
  int slot = wav*4 + quad;
  #pragma unroll
  for (int nt = 0; nt < 8; nt++) red[(nt*16 + l16)*17 + slot] = s1[nt];
  __syncthreads();
  if (tid < 128) {
    float s = 0.f;
    #pragma unroll
    for (int k = 0; k < 16; k++) s += red[tid*17 + k];
    atomicAdd(&st[ST_HC_SUM + tid], s);
  }
  __syncthreads();
  #pragma unroll
  for (int nt = 0; nt < 8; nt++) red[(nt*16 + l16)*17 + slot] = s2[nt];
  __syncthreads();
  if (tid < 128) {
    float s = 0.f;
    #pragma unroll
    for (int k = 0; k < 16; k++) s += red[tid*17 + k];
    atomicAdd(&st[ST_HC_SQ + tid], s);
  }
}

// ---- K67 v2: 8 nodes/block; sphere gather (BN of hc inline) -> LDS bf16 -> MFMA sconv ----
__global__ __launch_bounds__(256) void k67_sphconv(
    const unsigned* __restrict__ hcb2, const float* __restrict__ g, const float* __restrict__ be,
    const int* __restrict__ sph_idx, const float* __restrict__ sph_w,
    const int* __restrict__ ind0, const int* __restrict__ ind1, const int* __restrict__ ind2,
    const unsigned short* __restrict__ swb, const float* __restrict__ b_sc,
    float* __restrict__ y, float* __restrict__ st) {
  __shared__ unsigned short E[16*136];     // rows 0..7 valid; 8..15 unused garbage
  int tid = threadIdx.x;
  int gn0 = blockIdx.x*8;
  int nb0 = gn0 % NPB_;
  int s = nb0 < 1024 ? 0 : (nb0 < 1792 ? 1 : 2);
  int wv = tid >> 6, lane = tid & 63;
  int quad = lane >> 4, l16 = lane & 15;
  {
    int c0 = lane*2, c1 = c0 + 1;
    float n = (float)(B_*NBINS_);
    float m0 = st[ST_HC_SUM + c0]/n, m1 = st[ST_HC_SUM + c1]/n;
    float va0 = st[ST_HC_SQ + c0]/n - m0*m0, va1 = st[ST_HC_SQ + c1]/n - m1*m1;
    float a0 = g[c0]*rsqrtf(va0 + EPS_), a1 = g[c1]*rsqrtf(va1 + EPS_);
    float d0 = be[c0] - a0*m0, d1 = be[c1] - a1*m1;
    #pragma unroll
    for (int i = 0; i < 2; i++) {
      int node_l = wv*2 + i;
      int gn = gn0 + node_l;
      int b = gn / NPB_, nb = gn % NPB_;
      int v;
      if (nb < 1024) v = ind0[b*1024 + nb];
      else if (nb < 1792) v = ind1[b*768 + nb - 1024];
      else v = ind2[b*192 + nb - 1792];
      v = __builtin_amdgcn_readfirstlane(v);
      const unsigned* base = hcb2 + (size_t)b*NBINS_*64 + lane;
      float acc0 = 0.f, acc1 = 0.f;
      #pragma unroll
      for (int k = 0; k < 16; k++) {
        int mi = sph_idx[v*16 + k];
        float mw = sph_w[v*16 + k];
        unsigned dv = base[(size_t)mi*64];
        acc0 += mw * fmaxf(a0*b2f((unsigned short)(dv & 0xffff)) + d0, 0.f);
        acc1 += mw * fmaxf(a1*b2f((unsigned short)(dv >> 16)) + d1, 0.f);
      }
      unsigned lo = f2b(acc0), hi = f2b(acc1);
      *(unsigned*)&E[node_l*136 + c0] = lo | (hi << 16);
    }
  }
  __syncthreads();
  v4f acc = (v4f){0,0,0,0};
  const unsigned short* wb = swb + s*8192 + wv*512;
  #pragma unroll
  for (int kt = 0; kt < 4; kt++) {
    v8s a = *(const v8s*)&E[l16*136 + quad*8 + kt*32];
    v8s bf = *(const v8s*)&wb[kt*2048 + lane*8];
    acc = __builtin_amdgcn_mfma_f32_16x16x32_bf16(a, bf, acc, 0, 0, 0);
  }
  float bias = b_sc[s*64 + wv*16 + l16];
  float s1 = 0.f, s2 = 0.f;
  #pragma unroll
  for (int reg = 0; reg < 4; reg++) {
    int row = quad*4 + reg;
    if (quad < 2) {
      float val = acc[reg] + bias;
      y[(size_t)(gn0 + row)*64 + wv*16 + l16] = val;
      s1 += val; s2 += val*val;
    }
  }
  s1 += __shfl_xor(s1, 16);
  s2 += __shfl_xor(s2, 16);
  if (quad == 0) {
    atomicAdd(&st[ST_SC_SUM + s*64 + wv*16 + l16], s1);
    atomicAdd(&st[ST_SC_SQ  + s*64 + wv*16 + l16], s2);
  }
}

// ---- K10 v2: EdgeConv layer, 64 edges/block (496 blocks), bf16 MFMA ----
__global__ __launch_bounds__(256) void k10_dgcn(
    const void* __restrict__ xin_, unsigned short* __restrict__ xout,
    const int* __restrict__ edge0, const int* __restrict__ edge1, const int* __restrict__ edge2,
    const unsigned short* __restrict__ dwb, const float* __restrict__ db,
    const float* __restrict__ st, const float* __restrict__ scg, const float* __restrict__ scb,
    int layer, int usebn) {
  __shared__ unsigned short E[64*136];
  __shared__ float ash[64], dsh[64];
  int tid = threadIdx.x;
  int bid = blockIdx.x;
  int s, node_base, le_blk, span; const int* ec;
  if (bid < 256) {
    s = 0; int b = bid >> 7; node_base = b*NPB_; le_blk = (bid & 127)*64;
    span = 8192; ec = edge0 + b*2*8192;
  } else if (bid < 448) {
    int j = bid - 256; s = 1; int seg = j >> 5; int b = seg/3, vp = seg%3;
    node_base = b*NPB_ + 1024 + vp*256; le_blk = (j & 31)*64;
    span = 2048; ec = edge1 + ((b*3+vp)*2)*2048;
  } else {
    int j = bid - 448; s = 2; int seg = j >> 3; int b = seg/3, vp = seg%3;
    node_base = b*NPB_ + 1792 + vp*64; le_blk = (j & 7)*64;
    span = 512; ec = edge2 + ((b*3+vp)*2)*512;
  }
  const int* en = ec + span;
  if (usebn) {
    if (tid < 64) {
      float n = s==0 ? 2048.f : (s==1 ? 1536.f : 384.f);
      float m = st[ST_SC_SUM + s*64 + tid]/n;
      float var = st[ST_SC_SQ + s*64 + tid]/n - m*m;
      float a = scg[s*64 + tid]*rsqrtf(var + EPS_);
      ash[tid] = a; dsh[tid] = scb[s*64 + tid] - a*m;
    }
    __syncthreads();
  }
  {
    int e_l = tid >> 2, part = tid & 3;
    int h = part >> 1, cb = (part & 1)*32;
    int e = le_blk + e_l;
    int ci = ec[e], ni = en[e];
    if (usebn) {
      const float* xc = (const float*)xin_ + (size_t)(node_base + ci)*64 + cb;
      const float* xn = (const float*)xin_ + (size_t)(node_base + ni)*64 + cb;
      float4 xc4[8], xn4[8];
      #pragma unroll
      for (int q = 0; q < 8; q++) xc4[q] = *(const float4*)&xc[q*4];
      if (h) {
        #pragma unroll
        for (int q = 0; q < 8; q++) xn4[q] = *(const float4*)&xn[q*4];
      }
      #pragma unroll
      for (int c8 = 0; c8 < 32; c8 += 8) {
        v8s pk;
        #pragma unroll
        for (int j = 0; j < 8; j++) {
          int cl = c8 + j;
          int c = cb + cl;
          float xcv = ((const float*)xc4)[cl];
          float vc = fmaxf(ash[c]*xcv + dsh[c], 0.f);
          float val = vc;
          if (h) {
            float xnv = ((const float*)xn4)[cl];
            val = fmaxf(ash[c]*xnv + dsh[c], 0.f) - vc;
          }
          pk[j] = (short)f2b(val);
        }
        *(v8s*)&E[e_l*136 + h*64 + cb + c8] = pk;
      }
    } else {
      const unsigned short* xc = (const unsigned short*)xin_ + (size_t)(node_base + ci)*64 + cb;
      const unsigned short* xn = (const unsigned short*)xin_ + (size_t)(node_base + ni)*64 + cb;
      #pragma unroll
      for (int c8 = 0; c8 < 32; c8 += 8) {
        v8s vc8 = *(const v8s*)&xc[c8];
        v8s pk = vc8;
        if (h) {
          v8s vn8 = *(const v8s*)&xn[c8];
          #pragma unroll
          for (int j = 0; j < 8; j++)
            pk[j] = (short)f2b(b2f((unsigned short)vn8[j]) - b2f((unsigned short)vc8[j]));
        }
        *(v8s*)&E[e_l*136 + h*64 + cb + c8] = pk;
      }
    }
  }
  __syncthreads();
  int wave = tid >> 6, lane = tid & 63;
  int quad = lane >> 4, l16 = lane & 15;
  const unsigned short* wb = dwb + (size_t)(s*4 + layer)*8192;
  v4f acc[4];
  #pragma unroll
  for (int nt = 0; nt < 4; nt++) acc[nt] = (v4f){0,0,0,0};
  #pragma unroll
  for (int kt = 0; kt < 4; kt++) {
    v8s a = *(const v8s*)&E[(wave*16 + l16)*136 + quad*8 + kt*32];
    #pragma unroll
    for (int nt = 0; nt < 4; nt++) {
      v8s bf = *(const v8s*)&wb[((kt*4 + nt)*64 + lane)*8];
      acc[nt] = __builtin_amdgcn_mfma_f32_16x16x32_bf16(a, bf, acc[nt], 0, 0, 0);
    }
  }
  #pragma unroll
  for (int nt = 0; nt < 4; nt++) {
    float bias = db[(s*4 + layer)*64 + nt*16 + l16];
    float m = fmaxf(fmaxf(acc[nt][0], acc[nt][1]), fmaxf(acc[nt][2], acc[nt][3]));
    m = fmaxf(m + bias, 0.f);
    float other = __shfl_xor(m, 16);
    m = fmaxf(m, other);
    if ((quad & 1) == 0) {
      int node_l = wave*2 + (quad >> 1);
      xout[(size_t)(node_base + (le_blk >> 3) + node_l)*64 + nt*16 + l16] = f2b(m);
    }
  }
}

// ---- K11: head: logits, preds, BCE partials; LAST BLOCK finalizes losses ----
__global__ __launch_bounds__(256) void k11_head(
    const unsigned short* __restrict__ x, const float* __restrict__ hw, const float* __restrict__ hb,
    const int* __restrict__ t0, const int* __restrict__ t1, const int* __restrict__ t2,
    float* __restrict__ out, float* __restrict__ st) {
  __shared__ float shw[192];
  int tid = threadIdx.x;
  if (tid < 192) shw[tid] = hw[tid];
  __syncthreads();
  int gn = blockIdx.x*256 + tid;
  bool valid = gn < TOTN_;
  int g = valid ? gn : TOTN_-1;
  int b = g / NPB_, nb = g % NPB_;
  int s, tg;
  if (nb < 1024) { s = 0; tg = t0[b*1024 + nb]; }
  else if (nb < 1792) { s = 1; int j = nb-1024; tg = t1[(b*3 + (j>>8))*256 + (j&255)]; }
  else { s = 2; int j = nb-1792; tg = t2[(b*3 + (j>>6))*64 + (j&63)]; }
  const unsigned short* row = x + (size_t)g*64;
  float logit = hb[s];
  #pragma unroll
  for (int c8 = 0; c8 < 64; c8 += 8) {
    v8s v = *(const v8s*)&row[c8];
    #pragma unroll
    for (int j = 0; j < 8; j++)
      logit += b2f((unsigned short)v[j]) * shw[s*64 + c8 + j];
  }
  if (valid) out[6 + gn] = 1.f / (1.f + expf(-logit));
  float tf = (float)tg;
  float l = fmaxf(logit, 0.f) - logit*tf + log1pf(expf(-fabsf(logit)));
  float sp = (valid && tg) ? l : 0.f;
  float sn = (valid && !tg) ? l : 0.f;
  float cp = (valid && tg) ? 1.f : 0.f;
  float cn = (valid && !tg) ? 1.f : 0.f;
  for (int off = 32; off; off >>= 1) {
    sp += __shfl_down(sp, off);
    sn += __shfl_down(sn, off);
    cp += __shfl_down(cp, off);
    cn += __shfl_down(cn, off);
  }
  if ((tid & 63) == 0) {
    atomicAdd(&st[ST_LOSS + s*4 + 0], sp);
    atomicAdd(&st[ST_LOSS + s*4 + 1], sn);
    atomicAdd(&st[ST_LOSS + s*4 + 2], cp);
    atomicAdd(&st[ST_LOSS + s*4 + 3], cn);
  }
  __syncthreads();               // drains this block's atomics before ticket
  __threadfence();
  if (tid == 0) {
    unsigned t = (unsigned)atomicAdd(&st[ST_TICKET], 1.f);
    if (t >= 15) {
      #pragma unroll
      for (int i = 0; i < 6; i++) {
        int sc = i >> 1; int pos = !(i & 1);
        float sum = atomicAdd(&st[ST_LOSS + sc*4 + (pos ? 0 : 1)], 0.f);
        float cnt = atomicAdd(&st[ST_LOSS + sc*4 + (pos ? 2 : 3)], 0.f);
        out[i] = sum / fmaxf(cnt, 1.f);
      }
    }
  }
}

extern "C" void kernel_launch(void* const* d_in, const int* in_sizes, int n_in,
                              void* d_out, int out_size, void* d_ws, size_t ws_size,
                              hipStream_t stream) {
  const float* image  = (const float*)d_in[0];
  const float* bn_g   = (const float*)d_in[1];
  const float* bn_b   = (const float*)d_in[2];
  const int*   ht_idx = (const int*)  d_in[3];
  const float* ht_w   = (const float*)d_in[4];
  const float* w_conv = (const float*)d_in[5];
  const float* htbn_g = (const float*)d_in[6];
  const float* htbn_b = (const float*)d_in[7];
  const int*   sph_idx= (const int*)  d_in[8];
  const float* sph_w  = (const float*)d_in[9];
  const float* w_sc   = (const float*)d_in[10];
  const float* b_sc   = (const float*)d_in[11];
  const float* scbn_g = (const float*)d_in[12];
  const float* scbn_b = (const float*)d_in[13];
  const float* dgcn_w = (const float*)d_in[14];
  const float* dgcn_b = (const float*)d_in[15];
  const float* dgcn_hw= (const float*)d_in[16];
  const float* dgcn_hb= (const float*)d_in[17];
  const int*   ind0   = (const int*)  d_in[18];
  const int*   ind1   = (const int*)  d_in[19];
  const int*   ind2   = (const int*)  d_in[20];
  const int*   edge0  = (const int*)  d_in[21];
  const int*   edge1  = (const int*)  d_in[22];
  const int*   edge2  = (const int*)  d_in[23];
  const int*   t0     = (const int*)  d_in[24];
  const int*   t1     = (const int*)  d_in[25];
  const int*   t2     = (const int*)  d_in[26];
  float* out = (float*)d_out;

  char* ws = (char*)d_ws;
  unsigned short* x_t   = (unsigned short*)(ws);              //  8,388,608 B
  unsigned short* htb   = (unsigned short*)(ws +  8388608);   // 17,522,688 B (padded)
  unsigned short* hcb   = (unsigned short*)(ws + 25911296);   // 16,957,440 B
  unsigned short* wtb   = (unsigned short*)(ws + 42868736);   //    294,912 B
  unsigned short* dwb   = (unsigned short*)(ws + 43163648);   //    196,608 B
  unsigned short* swb   = (unsigned short*)(ws + 43360256);   //     49,152 B
  float*          y_sc  = (float*)(ws + 43409408);            //  1,015,808 B
  unsigned short* xdgA  = (unsigned short*)(ws + 44425216);   //    507,904 B
  unsigned short* xdgB  = (unsigned short*)(ws + 44933120);   //    507,904 B
  float*          st    = (float*)(ws + 45441024);            //     11,008 B

  kprep0<<<2637, 256, 0, stream>>>(w_conv, dgcn_w, w_sc, wtb, dwb, swb, (unsigned*)htb, image, st);
  k2_bnrelu_t<<<dim3(256,4,2), 256, 0, stream>>>(image, st, bn_g, bn_b, x_t);
  k3_hough<<<dim3(NBINS_/16, B_), 256, 0, stream>>>((const unsigned*)x_t, ht_idx, ht_w, (unsigned*)htb);
  k4_mfma<<<dim3(259, 2), 256, 0, stream>>>(htb, wtb, hcb, st);
  k67_sphconv<<<TOTN_/8, 256, 0, stream>>>((const unsigned*)hcb, htbn_g, htbn_b, sph_idx, sph_w,
                                           ind0, ind1, ind2, swb, b_sc, y_sc, st);
  k10_dgcn<<<496, 256, 0, stream>>>((const void*)y_sc, xdgA, edge0, edge1, edge2, dwb, dgcn_b, st, scbn_g, scbn_b, 0, 1);
  k10_dgcn<<<496, 256, 0, stream>>>((const void*)xdgA, xdgB, edge0, edge1, edge2, dwb, dgcn_b, st, scbn_g, scbn_b, 1, 0);
  k10_dgcn<<<496, 256, 0, stream>>>((const void*)xdgB, xdgA, edge0, edge1, edge2, dwb, dgcn_b, st, scbn_g, scbn_b, 2, 0);
  k10_dgcn<<<496, 256, 0, stream>>>((const void*)xdgA, xdgB, edge0, edge1, edge2, dwb, dgcn_b, st, scbn_g, scbn_b, 3, 0);
  k11_head<<<16, 256, 0, stream>>>(xdgB, dgcn_hw, dgcn_hb, t0, t1, t2, out, st);
}

// Round 15
// 235.454 us; speedup vs baseline: 1.1754x; 1.1754x over previous
//
#include <hip/hip_runtime.h>
#include <math.h>

#define B_ 2
#define C_ 128
#define NPIX_ 16384
#define HTH_ 184
#define HTW_ 180
#define NBINS_ 33120
#define PH_ 186
#define PW_ 184
#define NPB_ 1984
#define TOTN_ 3968
#define EPS_ 1e-5f

// stats region layout (floats)
#define ST_HC_SUM 0
#define ST_HC_SQ  128
#define ST_SC_SUM 256
#define ST_SC_SQ  448
#define ST_LOSS   640
#define ST_TICKET 652
#define ST_IMG_P1 704      // 8 chunks x 128 c
#define ST_IMG_P2 1728     // 8 chunks x 128 c

typedef __attribute__((ext_vector_type(8))) short v8s;
typedef __attribute__((ext_vector_type(4))) float v4f;

__device__ inline unsigned short f2b(float f) {
  unsigned u = __builtin_bit_cast(unsigned, f);
  unsigned r = u + 0x7fffu + ((u >> 16) & 1u);
  return (unsigned short)(r >> 16);
}
__device__ inline float b2f(unsigned short u) {
  unsigned v = ((unsigned)u) << 16;
  return __builtin_bit_cast(float, v);
}

// ---- KPREP0: weight permutes + htb border zero + img BN partials + st zero ----
__global__ void kprep0(const float* __restrict__ w, const float* __restrict__ dw,
                       const float* __restrict__ wsc,
                       unsigned short* __restrict__ wtb, unsigned short* __restrict__ dwb,
                       unsigned short* __restrict__ swb,
                       unsigned* __restrict__ htb2, const float* __restrict__ img,
                       float* __restrict__ st) {
  int bid = blockIdx.x;
  int tid = threadIdx.x;
  if (bid < 1612) {
    int idx = bid*256 + tid;
    if (idx < 147456) {
      int tap = idx >> 14, z = idx & 16383;
      int j = z & 7, lane = (z >> 3) & 63, nt = (z >> 9) & 7, kt = (z >> 12) & 3;
      int l = lane & 15, q = lane >> 4;
      int co = nt*16 + l, ci = kt*32 + q*8 + j;
      wtb[idx] = f2b(w[(tap*C_ + ci)*C_ + co]);
    } else if (idx < 245760) {
      int i2 = idx - 147456;                  // 98304
      int sl = i2 >> 13, z = i2 & 8191;
      int j = z & 7, lane = (z >> 3) & 63, nt = (z >> 9) & 3, kt = (z >> 11) & 3;
      int l = lane & 15, q = lane >> 4;
      int co = nt*16 + l, cc = kt*32 + q*8 + j;
      dwb[i2] = f2b(dw[(sl*128 + cc)*64 + co]);
    } else if (idx < 270336) {
      int i3 = idx - 245760;                  // 24576
      int s = i3 >> 13, z = i3 & 8191;
      int j = z & 7, lane = (z >> 3) & 63, nt = (z >> 9) & 3, kt = (z >> 11) & 3;
      int l = lane & 15, q = lane >> 4;
      int co = nt*16 + l, cc = kt*32 + q*8 + j;
      swb[i3] = f2b(wsc[(s*64 + co)*128 + cc]);
    } else if (idx < 412672) {
      int i = idx - 270336;                   // 142336
      int d = i & 63;
      int cell = i >> 6;                      // 2224
      int b = cell / 1112, j = cell % 1112;
      int y, x;
      if (j < 184) { y = 0; x = j; }
      else if (j < 368) { y = 185; x = j - 184; }
      else { int c = j - 368; int xi = c / 186; y = c % 186; x = xi == 0 ? 0 : 180 + xi; }
      htb2[((size_t)(b*PH_ + y)*PW_ + x)*64 + d] = 0u;
    }
  } else if (bid < 2636) {
    int kb = bid - 1612;                       // 1024 blocks: c = kb>>3, chunk = kb&7
    int c = kb >> 3, chunk = kb & 7;
    float s1 = 0.f, s2 = 0.f;
    for (int i = chunk*4096 + tid; i < (chunk+1)*4096; i += 256) {
      int b = i >> 14, p = i & (NPIX_-1);
      float v = img[((size_t)(b*C_ + c))*NPIX_ + p];
      s1 += v; s2 += v*v;
    }
    __shared__ float r1[256], r2[256];
    r1[tid] = s1; r2[tid] = s2; __syncthreads();
    for (int off = 128; off; off >>= 1) {
      if (tid < off) { r1[tid] += r1[tid+off]; r2[tid] += r2[tid+off]; }
      __syncthreads();
    }
    if (tid == 0) {
      st[ST_IMG_P1 + chunk*128 + c] = r1[0];
      st[ST_IMG_P2 + chunk*128 + c] = r2[0];
    }
  } else {
    // zero block: st[0..672) = HC/SC stats, LOSS, TICKET
    for (int i = tid; i < 672; i += 256) st[i] = 0.f;
  }
}

// ---- K2: img BN finalize + BN+ReLU + transpose NCHW -> bf16 [b][pix][c] ----
__global__ void k2_bnrelu_t(const float* __restrict__ img, const float* __restrict__ st,
                            const float* __restrict__ g, const float* __restrict__ be,
                            unsigned short* __restrict__ xt) {
  __shared__ float tile[32*65];
  __shared__ float ash[32], dsh[32];
  int p0 = blockIdx.x*64, c0 = blockIdx.y*32, b = blockIdx.z;
  int tid = threadIdx.x;
  if (tid < 32) {
    int c = c0 + tid;
    float s1 = 0.f, s2 = 0.f;
    #pragma unroll
    for (int ch = 0; ch < 8; ch++) {
      s1 += st[ST_IMG_P1 + ch*128 + c];
      s2 += st[ST_IMG_P2 + ch*128 + c];
    }
    float n = (float)(B_*NPIX_);
    float m = s1/n;
    float var = s2/n - m*m;
    float a = g[c]*rsqrtf(var + EPS_);
    ash[tid] = a; dsh[tid] = be[c] - a*m;
  }
  __syncthreads();
  for (int r = 0; r < 8; r++) {
    int flat = tid + r*256;
    int row = flat >> 6, col = flat & 63;
    float v = img[((size_t)(b*C_ + c0 + row))*NPIX_ + p0 + col];
    tile[row*65 + col] = fmaxf(ash[row]*v + dsh[row], 0.f);
  }
  __syncthreads();
  for (int r = 0; r < 4; r++) {
    int flat = (tid + r*256)*2;
    int pl = flat >> 5, cl = flat & 31;
    unsigned lo = f2b(tile[cl*65 + pl]);
    unsigned hi = f2b(tile[(cl+1)*65 + pl]);
    *(unsigned*)&xt[((size_t)b*NPIX_ + p0 + pl)*C_ + c0 + cl] = lo | (hi << 16);
  }
}

// ---- K3 v2: Hough gather, 4 bins/wave, 32 loads in flight ----
__global__ void k3_hough(const unsigned* __restrict__ xt2, const int* __restrict__ hidx,
                         const float* __restrict__ hwt, unsigned* __restrict__ htb2) {
  int tid = threadIdx.x;
  int wv = __builtin_amdgcn_readfirstlane(tid >> 6);
  int lane = tid & 63;
  int b = blockIdx.y;
  int bin0 = blockIdx.x*16 + wv*4;
  const unsigned* base = xt2 + (size_t)b*NPIX_*64 + lane;
  unsigned dv[4][8];
  #pragma unroll
  for (int i = 0; i < 4; i++) {
    #pragma unroll
    for (int k = 0; k < 8; k++) {
      int p = hidx[(bin0+i)*8 + k];
      dv[i][k] = base[(size_t)p*64];
    }
  }
  #pragma unroll
  for (int i = 0; i < 4; i++) {
    int bin = bin0 + i;
    float acc0 = 0.f, acc1 = 0.f;
    #pragma unroll
    for (int k = 0; k < 8; k++) {
      float w = hwt[bin*8 + k];
      acc0 += w * b2f((unsigned short)(dv[i][k] & 0xffff));
      acc1 += w * b2f((unsigned short)(dv[i][k] >> 16));
    }
    int y = bin / HTW_, x = bin - y*HTW_;
    htb2[((size_t)(b*PH_ + y + 1)*PW_ + (x+1))*64 + lane] =
        (unsigned)f2b(acc0) | (((unsigned)f2b(acc1)) << 16);
  }
}

// ---- K4 (R11 banked): wave = 32px x 128co; frag-order B in LDS; XCD-swizzled tiles ----
__global__ __launch_bounds__(256, 3) void k4_mfma(
    const unsigned short* __restrict__ htb, const unsigned short* __restrict__ wtb,
    unsigned short* __restrict__ hcb, float* __restrict__ st) {
  __shared__ char smem[32768];             // 32 KB: tap weights; reused as red[] in epilogue
  // XCD swizzle: consecutive bid round-robin across XCDs; give each XCD a contiguous band
  int tile = (blockIdx.x & 7)*33 + (blockIdx.x >> 3);
  if (tile >= 259) return;
  int tid = threadIdx.x;
  int wav = tid >> 6, lane = tid & 63;
  int quad = lane >> 4, l16 = lane & 15;
  int b = blockIdx.y;
  int p0 = tile*128 + wav*32;
  size_t ab[2];
  #pragma unroll
  for (int t = 0; t < 2; t++) {
    int px = p0 + t*16 + l16; if (px > NBINS_-1) px = NBINS_-1;
    int y = px / HTW_, x = px % HTW_;
    ab[t] = (((size_t)(b*PH_ + y))*PW_ + x)*C_ + quad*8;
  }
  v4f acc[2][8];
  #pragma unroll
  for (int t = 0; t < 2; t++)
    #pragma unroll
    for (int nt = 0; nt < 8; nt++) acc[t][nt] = (v4f){0,0,0,0};

  for (int tap = 0; tap < 9; tap++) {
    __syncthreads();
    const uint4* src = (const uint4*)(wtb + tap*16384);
    uint4* dst = (uint4*)smem;
    #pragma unroll
    for (int s = 0; s < 8; s++) dst[tid + s*256] = src[tid + s*256];
    __syncthreads();
    int dy = tap/3, dx = tap - dy*3;
    int toff = (dy*PW_ + dx)*C_;
    // all 8 A-loads issued up-front: L2 latency overlaps the 32 LDS reads
    v8s a[2][4];
    #pragma unroll
    for (int t = 0; t < 2; t++)
      #pragma unroll
      for (int kt = 0; kt < 4; kt++)
        a[t][kt] = *(const v8s*)&htb[ab[t] + toff + kt*32];
    #pragma unroll
    for (int kt = 0; kt < 4; kt++) {
      #pragma unroll
      for (int nt = 0; nt < 8; nt++) {
        v8s bf = *(const v8s*)(smem + ((((kt*8 + nt)*64) + lane) << 4));
        acc[0][nt] = __builtin_amdgcn_mfma_f32_16x16x32_bf16(a[0][kt], bf, acc[0][nt], 0, 0, 0);
        acc[1][nt] = __builtin_amdgcn_mfma_f32_16x16x32_bf16(a[1][kt], bf, acc[1][nt], 0, 0, 0);
      }
    }
  }
  // epilogue: bf16 store + fused channel stats. D: row=quad*4+reg, col=l16
  __syncthreads();
  float* red = (float*)smem;               // 128*17 floats = 8.7 KB
  float s1[8], s2[8];
  #pragma unroll
  for (int nt = 0; nt < 8; nt++) { s1[nt] = 0.f; s2[nt] = 0.f; }
  #pragma unroll
  for (int t = 0; t < 2; t++) {
    int pbase = p0 + t*16 + quad*4;
    #pragma unroll
    for (int nt = 0; nt < 8; nt++) {
      int co = nt*16 + l16;
      #pragma unroll
      for (int reg = 0; reg < 4; reg++) {
        int po = pbase + reg;
        if (po < NBINS_) {
          float v = acc[t][nt][reg];
          hcb[((size_t)b*NBINS_ + po)*C_ + co] = f2b(v);
          s1[nt] += v; s2[nt] += v*v;
        }
      }
    }
  }
  int slot = wav*4 + quad;
  #pragma unroll
  for (int nt = 0; nt < 8; nt++) red[(nt*16 + l16)*17 + slot] = s1[nt];
  __syncthreads();
  if (tid < 128) {
    float s = 0.f;
    #pragma unroll
    for (int k = 0; k < 16; k++) s += red[tid*17 + k];
    atomicAdd(&st[ST_HC_SUM + tid], s);
  }
  __syncthreads();
  #pragma unroll
  for (int nt = 0; nt < 8; nt++) red[(nt*16 + l16)*17 + slot] = s2[nt];
  __syncthreads();
  if (tid < 128) {
    float s = 0.f;
    #pragma unroll
    for (int k = 0; k < 16; k++) s += red[tid*17 + k];
    atomicAdd(&st[ST_HC_SQ + tid], s);
  }
}

// ---- K67 v2: 8 nodes/block; sphere gather (BN of hc inline) -> LDS bf16 -> MFMA sconv ----
__global__ __launch_bounds__(256) void k67_sphconv(
    const unsigned* __restrict__ hcb2, const float* __restrict__ g, const float* __restrict__ be,
    const int* __restrict__ sph_idx, const float* __restrict__ sph_w,
    const int* __restrict__ ind0, const int* __restrict__ ind1, const int* __restrict__ ind2,
    const unsigned short* __restrict__ swb, const float* __restrict__ b_sc,
    float* __restrict__ y, float* __restrict__ st) {
  __shared__ unsigned short E[16*136];     // rows 0..7 valid; 8..15 unused garbage
  int tid = threadIdx.x;
  int gn0 = blockIdx.x*8;
  int nb0 = gn0 % NPB_;
  int s = nb0 < 1024 ? 0 : (nb0 < 1792 ? 1 : 2);
  int wv = tid >> 6, lane = tid & 63;
  int quad = lane >> 4, l16 = lane & 15;
  {
    int c0 = lane*2, c1 = c0 + 1;
    float n = (float)(B_*NBINS_);
    float m0 = st[ST_HC_SUM + c0]/n, m1 = st[ST_HC_SUM + c1]/n;
    float va0 = st[ST_HC_SQ + c0]/n - m0*m0, va1 = st[ST_HC_SQ + c1]/n - m1*m1;
    float a0 = g[c0]*rsqrtf(va0 + EPS_), a1 = g[c1]*rsqrtf(va1 + EPS_);
    float d0 = be[c0] - a0*m0, d1 = be[c1] - a1*m1;
    #pragma unroll
    for (int i = 0; i < 2; i++) {
      int node_l = wv*2 + i;
      int gn = gn0 + node_l;
      int b = gn / NPB_, nb = gn % NPB_;
      int v;
      if (nb < 1024) v = ind0[b*1024 + nb];
      else if (nb < 1792) v = ind1[b*768 + nb - 1024];
      else v = ind2[b*192 + nb - 1792];
      v = __builtin_amdgcn_readfirstlane(v);
      const unsigned* base = hcb2 + (size_t)b*NBINS_*64 + lane;
      float acc0 = 0.f, acc1 = 0.f;
      #pragma unroll
      for (int k = 0; k < 16; k++) {
        int mi = sph_idx[v*16 + k];
        float mw = sph_w[v*16 + k];
        unsigned dv = base[(size_t)mi*64];
        acc0 += mw * fmaxf(a0*b2f((unsigned short)(dv & 0xffff)) + d0, 0.f);
        acc1 += mw * fmaxf(a1*b2f((unsigned short)(dv >> 16)) + d1, 0.f);
      }
      unsigned lo = f2b(acc0), hi = f2b(acc1);
      *(unsigned*)&E[node_l*136 + c0] = lo | (hi << 16);
    }
  }
  __syncthreads();
  v4f acc = (v4f){0,0,0,0};
  const unsigned short* wb = swb + s*8192 + wv*512;
  #pragma unroll
  for (int kt = 0; kt < 4; kt++) {
    v8s a = *(const v8s*)&E[l16*136 + quad*8 + kt*32];
    v8s bf = *(const v8s*)&wb[kt*2048 + lane*8];
    acc = __builtin_amdgcn_mfma_f32_16x16x32_bf16(a, bf, acc, 0, 0, 0);
  }
  float bias = b_sc[s*64 + wv*16 + l16];
  float s1 = 0.f, s2 = 0.f;
  #pragma unroll
  for (int reg = 0; reg < 4; reg++) {
    int row = quad*4 + reg;
    if (quad < 2) {
      float val = acc[reg] + bias;
      y[(size_t)(gn0 + row)*64 + wv*16 + l16] = val;
      s1 += val; s2 += val*val;
    }
  }
  s1 += __shfl_xor(s1, 16);
  s2 += __shfl_xor(s2, 16);
  if (quad == 0) {
    atomicAdd(&st[ST_SC_SUM + s*64 + wv*16 + l16], s1);
    atomicAdd(&st[ST_SC_SQ  + s*64 + wv*16 + l16], s2);
  }
}

// ---- K10 v2: EdgeConv layer, 64 edges/block (496 blocks), bf16 MFMA ----
__global__ __launch_bounds__(256) void k10_dgcn(
    const void* __restrict__ xin_, unsigned short* __restrict__ xout,
    const int* __restrict__ edge0, const int* __restrict__ edge1, const int* __restrict__ edge2,
    const unsigned short* __restrict__ dwb, const float* __restrict__ db,
    const float* __restrict__ st, const float* __restrict__ scg, const float* __restrict__ scb,
    int layer, int usebn) {
  __shared__ unsigned short E[64*136];
  __shared__ float ash[64], dsh[64];
  int tid = threadIdx.x;
  int bid = blockIdx.x;
  int s, node_base, le_blk, span; const int* ec;
  if (bid < 256) {
    s = 0; int b = bid >> 7; node_base = b*NPB_; le_blk = (bid & 127)*64;
    span = 8192; ec = edge0 + b*2*8192;
  } else if (bid < 448) {
    int j = bid - 256; s = 1; int seg = j >> 5; int b = seg/3, vp = seg%3;
    node_base = b*NPB_ + 1024 + vp*256; le_blk = (j & 31)*64;
    span = 2048; ec = edge1 + ((b*3+vp)*2)*2048;
  } else {
    int j = bid - 448; s = 2; int seg = j >> 3; int b = seg/3, vp = seg%3;
    node_base = b*NPB_ + 1792 + vp*64; le_blk = (j & 7)*64;
    span = 512; ec = edge2 + ((b*3+vp)*2)*512;
  }
  const int* en = ec + span;
  if (usebn) {
    if (tid < 64) {
      float n = s==0 ? 2048.f : (s==1 ? 1536.f : 384.f);
      float m = st[ST_SC_SUM + s*64 + tid]/n;
      float var = st[ST_SC_SQ + s*64 + tid]/n - m*m;
      float a = scg[s*64 + tid]*rsqrtf(var + EPS_);
      ash[tid] = a; dsh[tid] = scb[s*64 + tid] - a*m;
    }
    __syncthreads();
  }
  {
    int e_l = tid >> 2, part = tid & 3;
    int h = part >> 1, cb = (part & 1)*32;
    int e = le_blk + e_l;
    int ci = ec[e], ni = en[e];
    if (usebn) {
      const float* xc = (const float*)xin_ + (size_t)(node_base + ci)*64 + cb;
      const float* xn = (const float*)xin_ + (size_t)(node_base + ni)*64 + cb;
      float4 xc4[8], xn4[8];
      #pragma unroll
      for (int q = 0; q < 8; q++) xc4[q] = *(const float4*)&xc[q*4];
      if (h) {
        #pragma unroll
        for (int q = 0; q < 8; q++) xn4[q] = *(const float4*)&xn[q*4];
      }
      #pragma unroll
      for (int c8 = 0; c8 < 32; c8 += 8) {
        v8s pk;
        #pragma unroll
        for (int j = 0; j < 8; j++) {
          int cl = c8 + j;
          int c = cb + cl;
          float xcv = ((const float*)xc4)[cl];
          float vc = fmaxf(ash[c]*xcv + dsh[c], 0.f);
          float val = vc;
          if (h) {
            float xnv = ((const float*)xn4)[cl];
            val = fmaxf(ash[c]*xnv + dsh[c], 0.f) - vc;
          }
          pk[j] = (short)f2b(val);
        }
        *(v8s*)&E[e_l*136 + h*64 + cb + c8] = pk;
      }
    } else {
      const unsigned short* xc = (const unsigned short*)xin_ + (size_t)(node_base + ci)*64 + cb;
      const unsigned short* xn = (const unsigned short*)xin_ + (size_t)(node_base + ni)*64 + cb;
      #pragma unroll
      for (int c8 = 0; c8 < 32; c8 += 8) {
        v8s vc8 = *(const v8s*)&xc[c8];
        v8s pk = vc8;
        if (h) {
          v8s vn8 = *(const v8s*)&xn[c8];
          #pragma unroll
          for (int j = 0; j < 8; j++)
            pk[j] = (short)f2b(b2f((unsigned short)vn8[j]) - b2f((unsigned short)vc8[j]));
        }
        *(v8s*)&E[e_l*136 + h*64 + cb + c8] = pk;
      }
    }
  }
  __syncthreads();
  int wave = tid >> 6, lane = tid & 63;
  int quad = lane >> 4, l16 = lane & 15;
  const unsigned short* wb = dwb + (size_t)(s*4 + layer)*8192;
  v4f acc[4];
  #pragma unroll
  for (int nt = 0; nt < 4; nt++) acc[nt] = (v4f){0,0,0,0};
  #pragma unroll
  for (int kt = 0; kt < 4; kt++) {
    v8s a = *(const v8s*)&E[(wave*16 + l16)*136 + quad*8 + kt*32];
    #pragma unroll
    for (int nt = 0; nt < 4; nt++) {
      v8s bf = *(const v8s*)&wb[((kt*4 + nt)*64 + lane)*8];
      acc[nt] = __builtin_amdgcn_mfma_f32_16x16x32_bf16(a, bf, acc[nt], 0, 0, 0);
    }
  }
  #pragma unroll
  for (int nt = 0; nt < 4; nt++) {
    float bias = db[(s*4 + layer)*64 + nt*16 + l16];
    float m = fmaxf(fmaxf(acc[nt][0], acc[nt][1]), fmaxf(acc[nt][2], acc[nt][3]));
    m = fmaxf(m + bias, 0.f);
    float other = __shfl_xor(m, 16);
    m = fmaxf(m, other);
    if ((quad & 1) == 0) {
      int node_l = wave*2 + (quad >> 1);
      xout[(size_t)(node_base + (le_blk >> 3) + node_l)*64 + nt*16 + l16] = f2b(m);
    }
  }
}

// ---- K11: head: logits, preds, BCE partials; LAST BLOCK finalizes losses ----
__global__ __launch_bounds__(256) void k11_head(
    const unsigned short* __restrict__ x, const float* __restrict__ hw, const float* __restrict__ hb,
    const int* __restrict__ t0, const int* __restrict__ t1, const int* __restrict__ t2,
    float* __restrict__ out, float* __restrict__ st) {
  __shared__ float shw[192];
  int tid = threadIdx.x;
  if (tid < 192) shw[tid] = hw[tid];
  __syncthreads();
  int gn = blockIdx.x*256 + tid;
  bool valid = gn < TOTN_;
  int g = valid ? gn : TOTN_-1;
  int b = g / NPB_, nb = g % NPB_;
  int s, tg;
  if (nb < 1024) { s = 0; tg = t0[b*1024 + nb]; }
  else if (nb < 1792) { s = 1; int j = nb-1024; tg = t1[(b*3 + (j>>8))*256 + (j&255)]; }
  else { s = 2; int j = nb-1792; tg = t2[(b*3 + (j>>6))*64 + (j&63)]; }
  const unsigned short* row = x + (size_t)g*64;
  float logit = hb[s];
  #pragma unroll
  for (int c8 = 0; c8 < 64; c8 += 8) {
    v8s v = *(const v8s*)&row[c8];
    #pragma unroll
    for (int j = 0; j < 8; j++)
      logit += b2f((unsigned short)v[j]) * shw[s*64 + c8 + j];
  }
  if (valid) out[6 + gn] = 1.f / (1.f + expf(-logit));
  float tf = (float)tg;
  float l = fmaxf(logit, 0.f) - logit*tf + log1pf(expf(-fabsf(logit)));
  float sp = (valid && tg) ? l : 0.f;
  float sn = (valid && !tg) ? l : 0.f;
  float cp = (valid && tg) ? 1.f : 0.f;
  float cn = (valid && !tg) ? 1.f : 0.f;
  for (int off = 32; off; off >>= 1) {
    sp += __shfl_down(sp, off);
    sn += __shfl_down(sn, off);
    cp += __shfl_down(cp, off);
    cn += __shfl_down(cn, off);
  }
  if ((tid & 63) == 0) {
    atomicAdd(&st[ST_LOSS + s*4 + 0], sp);
    atomicAdd(&st[ST_LOSS + s*4 + 1], sn);
    atomicAdd(&st[ST_LOSS + s*4 + 2], cp);
    atomicAdd(&st[ST_LOSS + s*4 + 3], cn);
  }
  __syncthreads();               // drains this block's atomics before ticket
  __threadfence();
  if (tid == 0) {
    unsigned t = (unsigned)atomicAdd(&st[ST_TICKET], 1.f);
    if (t >= 15) {
      #pragma unroll
      for (int i = 0; i < 6; i++) {
        int sc = i >> 1; int pos = !(i & 1);
        float sum = atomicAdd(&st[ST_LOSS + sc*4 + (pos ? 0 : 1)], 0.f);
        float cnt = atomicAdd(&st[ST_LOSS + sc*4 + (pos ? 2 : 3)], 0.f);
        out[i] = sum / fmaxf(cnt, 1.f);
      }
    }
  }
}

extern "C" void kernel_launch(void* const* d_in, const int* in_sizes, int n_in,
                              void* d_out, int out_size, void* d_ws, size_t ws_size,
                              hipStream_t stream) {
  const float* image  = (const float*)d_in[0];
  const float* bn_g   = (const float*)d_in[1];
  const float* bn_b   = (const float*)d_in[2];
  const int*   ht_idx = (const int*)  d_in[3];
  const float* ht_w   = (const float*)d_in[4];
  const float* w_conv = (const float*)d_in[5];
  const float* htbn_g = (const float*)d_in[6];
  const float* htbn_b = (const float*)d_in[7];
  const int*   sph_idx= (const int*)  d_in[8];
  const float* sph_w  = (const float*)d_in[9];
  const float* w_sc   = (const float*)d_in[10];
  const float* b_sc   = (const float*)d_in[11];
  const float* scbn_g = (const float*)d_in[12];
  const float* scbn_b = (const float*)d_in[13];
  const float* dgcn_w = (const float*)d_in[14];
  const float* dgcn_b = (const float*)d_in[15];
  const float* dgcn_hw= (const float*)d_in[16];
  const float* dgcn_hb= (const float*)d_in[17];
  const int*   ind0   = (const int*)  d_in[18];
  const int*   ind1   = (const int*)  d_in[19];
  const int*   ind2   = (const int*)  d_in[20];
  const int*   edge0  = (const int*)  d_in[21];
  const int*   edge1  = (const int*)  d_in[22];
  const int*   edge2  = (const int*)  d_in[23];
  const int*   t0     = (const int*)  d_in[24];
  const int*   t1     = (const int*)  d_in[25];
  const int*   t2     = (const int*)  d_in[26];
  float* out = (float*)d_out;

  char* ws = (char*)d_ws;
  unsigned short* x_t   = (unsigned short*)(ws);              //  8,388,608 B
  unsigned short* htb   = (unsigned short*)(ws +  8388608);   // 17,522,688 B (padded)
  unsigned short* hcb   = (unsigned short*)(ws + 25911296);   // 16,957,440 B
  unsigned short* wtb   = (unsigned short*)(ws + 42868736);   //    294,912 B
  unsigned short* dwb   = (unsigned short*)(ws + 43163648);   //    196,608 B
  unsigned short* swb   = (unsigned short*)(ws + 43360256);   //     49,152 B
  float*          y_sc  = (float*)(ws + 43409408);            //  1,015,808 B
  unsigned short* xdgA  = (unsigned short*)(ws + 44425216);   //    507,904 B
  unsigned short* xdgB  = (unsigned short*)(ws + 44933120);   //    507,904 B
  float*          st    = (float*)(ws + 45441024);            //     11,008 B

  kprep0<<<2637, 256, 0, stream>>>(w_conv, dgcn_w, w_sc, wtb, dwb, swb, (unsigned*)htb, image, st);
  k2_bnrelu_t<<<dim3(256,4,2), 256, 0, stream>>>(image, st, bn_g, bn_b, x_t);
  k3_hough<<<dim3(NBINS_/16, B_), 256, 0, stream>>>((const unsigned*)x_t, ht_idx, ht_w, (unsigned*)htb);
  k4_mfma<<<dim3(264, 2), 256, 0, stream>>>(htb, wtb, hcb, st);
  k67_sphconv<<<TOTN_/8, 256, 0, stream>>>((const unsigned*)hcb, htbn_g, htbn_b, sph_idx, sph_w,
                                           ind0, ind1, ind2, swb, b_sc, y_sc, st);
  k10_dgcn<<<496, 256, 0, stream>>>((const void*)y_sc, xdgA, edge0, edge1, edge2, dwb, dgcn_b, st, scbn_g, scbn_b, 0, 1);
  k10_dgcn<<<496, 256, 0, stream>>>((const void*)xdgA, xdgB, edge0, edge1, edge2, dwb, dgcn_b, st, scbn_g, scbn_b, 1, 0);
  k10_dgcn<<<496, 256, 0, stream>>>((const void*)xdgB, xdgA, edge0, edge1, edge2, dwb, dgcn_b, st, scbn_g, scbn_b, 2, 0);
  k10_dgcn<<<496, 256, 0, stream>>>((const void*)xdgA, xdgB, edge0, edge1, edge2, dwb, dgcn_b, st, scbn_g, scbn_b, 3, 0);
  k11_head<<<16, 256, 0, stream>>>(xdgB, dgcn_hw, dgcn_hb, t0, t1, t2, out, st);
}